// Round 10
// baseline (364.877 us; speedup 1.0000x reference)
//
#include <hip/hip_runtime.h>
#include <hip/hip_bf16.h>

#define NN 50000
#define EE 600000
#define RR 8
#define NSEG (NN*RR)                     // 400000
#define NB_SCAN ((NSEG + 1023)/1024)     // 391
#define LDSH 12288                       // shorts per buffer (A 4096 | B 8192)

typedef unsigned int u32;
typedef __attribute__((ext_vector_type(8))) short bf16x8;
typedef __attribute__((ext_vector_type(4))) float f32x4;
typedef __attribute__((ext_vector_type(4))) u32 u32x4;

// fp32 -> bf16 round-to-nearest-even (finite inputs only)
__device__ inline unsigned short f2bf(float f){
  u32 u = __float_as_uint(f);
  u32 r = (u + 0x7fffu + ((u >> 16) & 1u)) >> 16;
  return (unsigned short)r;
}
__device__ inline float bf2f(unsigned short b){ return __uint_as_float((u32)b << 16); }

#define GLD16(g, l)  __builtin_amdgcn_global_load_lds( \
    (const __attribute__((address_space(1))) void*)(g), \
    (__attribute__((address_space(3))) void*)(l), 16, 0, 0)

// ---------------- conversion: fp32 -> bf16, 4 elems/thread ----------------
__global__ void cvt_k(const float* __restrict__ in, unsigned short* __restrict__ out, int n4){
  int i = blockIdx.x * 256 + threadIdx.x;
  if (i >= n4) return;
  float4 v = ((const float4*)in)[i];
  ushort4 o;
  o.x = f2bf(v.x); o.y = f2bf(v.y); o.z = f2bf(v.z); o.w = f2bf(v.w);
  ((ushort4*)out)[i] = o;
}

// ---------------- pack B (W stack) into MFMA fragment order ----------------
// frag id = k32*8 + nf; within frag: lane*8 + i
// element: B[k32*32 + (lane>>4)*8 + i][nf*16 + (lane&15)]
__global__ void pack_k(const float* __restrict__ Wrel, const float* __restrict__ root,
                       short* __restrict__ Bp, int nk32, int krel){
  int tid = blockIdx.x * 256 + threadIdx.x;
  if (tid >= nk32 * 512) return;
  int lane = tid & 63;
  int nf   = (tid >> 6) & 7;
  int k32  = tid >> 9;
  int col  = nf * 16 + (lane & 15);
  short vals[8];
#pragma unroll
  for (int i = 0; i < 8; ++i){
    int kk = k32 * 32 + ((lane >> 4) << 3) + i;
    float f = (kk < krel) ? Wrel[(size_t)kk * 128 + col]
                          : root[(size_t)(kk - krel) * 128 + col];
    vals[i] = (short)f2bf(f);
  }
  *(bf16x8*)(Bp + (size_t)tid * 8) = *(const bf16x8*)vals;
}

// ---------------- CSR build (relation-major: seg = r*NN + dst) -------------
__global__ void count_k(const int* __restrict__ dst, const int* __restrict__ et,
                        u32* __restrict__ cnt){
  int e = blockIdx.x * 256 + threadIdx.x;
  if (e >= EE) return;
  atomicAdd(&cnt[(size_t)et[e] * NN + dst[e]], 1u);
}

__global__ void scan1_k(const u32* __restrict__ cnt, u32* __restrict__ offs, u32* __restrict__ bsum){
  __shared__ u32 s[512];
  int t = threadIdx.x;                       // 256 threads
  int base = blockIdx.x * 1024 + t * 4;
  u32 loc[4]; u32 sum = 0;
#pragma unroll
  for (int i = 0; i < 4; ++i){ loc[i] = (base + i < NSEG) ? cnt[base + i] : 0u; sum += loc[i]; }
  int pb = 0;
  s[t] = sum; __syncthreads();
  for (int off = 1; off < 256; off <<= 1){
    u32 v = s[pb * 256 + t];
    if (t >= off) v += s[pb * 256 + t - off];
    s[(pb ^ 1) * 256 + t] = v; pb ^= 1; __syncthreads();
  }
  u32 incl = s[pb * 256 + t];
  u32 excl = incl - sum;
  if (t == 255) bsum[blockIdx.x] = incl;
  u32 run = excl;
#pragma unroll
  for (int i = 0; i < 4; ++i){ if (base + i < NSEG) offs[base + i] = run; run += loc[i]; }
}

__global__ void scan2_k(u32* __restrict__ bsum){
  __shared__ u32 s[1024];
  int t = threadIdx.x;                       // 512 threads
  u32 v = (t < NB_SCAN) ? bsum[t] : 0u;
  int pb = 0;
  s[t] = v; __syncthreads();
  for (int off = 1; off < 512; off <<= 1){
    u32 x = s[pb * 512 + t];
    if (t >= off) x += s[pb * 512 + t - off];
    s[(pb ^ 1) * 512 + t] = x; pb ^= 1; __syncthreads();
  }
  u32 incl = s[pb * 512 + t];
  if (t < NB_SCAN) bsum[t] = incl - v;       // exclusive
}

__global__ void scan3_k(u32* __restrict__ offs, const u32* __restrict__ bsum){
  int t = threadIdx.x;
  int base = blockIdx.x * 1024 + t * 4;
  u32 add = bsum[blockIdx.x];
#pragma unroll
  for (int i = 0; i < 4; ++i){ if (base + i < NSEG) offs[base + i] += add; }
  if (blockIdx.x == 0 && t == 0) offs[NSEG] = EE;
}

// fill: reuse cnt as cursor (atomicSub)
__global__ void fill_k(const int* __restrict__ src, const int* __restrict__ dst,
                       const int* __restrict__ et, const u32* __restrict__ offs,
                       u32* __restrict__ cnt, int* __restrict__ elist){
  int e = blockIdx.x * 256 + threadIdx.x;
  if (e >= EE) return;
  int s = et[e] * NN + dst[e];
  u32 p = atomicSub(&cnt[s], 1u);
  elist[offs[s] + p - 1] = src[e];
}

// ------- per-(relation,dst) mean aggregation -> a[R][NN][128] bf16 ----------
// 8-lane group per segment, 32 segments/block; lane owns 32 B of the row.
__launch_bounds__(256, 8)
__global__ void agg_k(const u32* __restrict__ offs, const int* __restrict__ elist,
                      const unsigned short* __restrict__ h, unsigned short* __restrict__ a){
  int t = threadIdx.x;
  int g = t >> 3, ll8 = t & 7;
  int seg = blockIdx.x * 32 + g;
  u32 beg = offs[seg], end = offs[seg + 1];
  float s[16];
#pragma unroll
  for (int i = 0; i < 16; ++i) s[i] = 0.f;
  const unsigned short* hb = h + (size_t)ll8 * 16;
  u32 e = beg;
  for (; e + 2 <= end; e += 2){
    int s0 = elist[e], s1 = elist[e + 1];
    const unsigned short* r0 = hb + (size_t)s0 * 128;
    const unsigned short* r1 = hb + (size_t)s1 * 128;
    u32x4 p00 = *(const u32x4*)r0, p01 = *(const u32x4*)(r0 + 8);
    u32x4 p10 = *(const u32x4*)r1, p11 = *(const u32x4*)(r1 + 8);
#pragma unroll
    for (int i = 0; i < 4; ++i){
      s[2*i]     += __uint_as_float(p00[i] << 16)         + __uint_as_float(p10[i] << 16);
      s[2*i+1]   += __uint_as_float(p00[i] & 0xffff0000u) + __uint_as_float(p10[i] & 0xffff0000u);
      s[8+2*i]   += __uint_as_float(p01[i] << 16)         + __uint_as_float(p11[i] << 16);
      s[8+2*i+1] += __uint_as_float(p01[i] & 0xffff0000u) + __uint_as_float(p11[i] & 0xffff0000u);
    }
  }
  if (e < end){
    int s0 = elist[e];
    const unsigned short* r0 = hb + (size_t)s0 * 128;
    u32x4 p00 = *(const u32x4*)r0, p01 = *(const u32x4*)(r0 + 8);
#pragma unroll
    for (int i = 0; i < 4; ++i){
      s[2*i]     += __uint_as_float(p00[i] << 16);
      s[2*i+1]   += __uint_as_float(p00[i] & 0xffff0000u);
      s[8+2*i]   += __uint_as_float(p01[i] << 16);
      s[8+2*i+1] += __uint_as_float(p01[i] & 0xffff0000u);
    }
  }
  u32 deg = end - beg;
  if (deg){
    float inv = 1.f / (float)deg;
#pragma unroll
    for (int i = 0; i < 16; ++i) s[i] *= inv;
  }
  u32x4 o0, o1;
#pragma unroll
  for (int i = 0; i < 4; ++i){
    o0[i] = (u32)f2bf(s[2*i])   | ((u32)f2bf(s[2*i+1])   << 16);
    o1[i] = (u32)f2bf(s[8+2*i]) | ((u32)f2bf(s[8+2*i+1]) << 16);
  }
  unsigned short* ap = a + (size_t)seg * 128 + ll8 * 16;
  *(u32x4*)ap = o0;
  *(u32x4*)(ap + 8) = o1;
}

// ---------------- res projection: resb = bf16(x @ res_w + res_b) ----------
__launch_bounds__(256, 4)
__global__ void resg_k(const unsigned short* __restrict__ xb, const short* __restrict__ Bp,
                       const float* __restrict__ rb, unsigned short* __restrict__ resb){
  const int tid = threadIdx.x;
  const int w = tid >> 6, l = tid & 63;
  const int sub = l >> 4, llr = l & 15;
  const int rowbase = blockIdx.x * 64 + w * 16;
  int vr = rowbase + llr; if (vr > NN - 1) vr = NN - 1;
  f32x4 acc[8] = {};
#pragma unroll
  for (int t = 0; t < 4; ++t){
    bf16x8 af = *(const bf16x8*)(xb + (size_t)vr * 128 + (t * 4 + sub) * 8);
    const short* bb = Bp + (size_t)(t * 8) * 512 + l * 8;
#pragma unroll
    for (int nf = 0; nf < 8; ++nf){
      bf16x8 bq = *(const bf16x8*)(bb + nf * 512);
      acc[nf] = __builtin_amdgcn_mfma_f32_16x16x32_bf16(af, bq, acc[nf], 0, 0, 0);
    }
  }
  const int lr = l >> 4, lc = l & 15;
#pragma unroll
  for (int nf = 0; nf < 8; ++nf){
    int col = nf * 16 + lc;
    float bv = rb[col];
#pragma unroll
    for (int r = 0; r < 4; ++r){
      int row = rowbase + lr * 4 + r;
      if (row < NN) resb[(size_t)row * 128 + col] = f2bf(acc[nf][r] + bv);
    }
  }
}

// -------- MFMA GEMM: async staging + 2-phase LDS double-buffer --------------
// BM=64, BN=128, BK=64. 4 waves: wave (wm,wn) owns 32 rows x 64 cols.
// Per kt: issue next tile's 6 GLD16 into buf^1, compute current from buf,
// ONE __syncthreads (its vmcnt(0) waits on loads that ran during compute).
template<int OUTMODE>
__launch_bounds__(256, 3)
__global__ void gemm_k(const unsigned short* __restrict__ Aa,   // [R][NN][128]
                       const unsigned short* __restrict__ Ah,   // [NN][128]
                       const short* __restrict__ Bp,            // 18*8192 shorts packed
                       const float* __restrict__ bias,
                       const unsigned short* __restrict__ resb,
                       float* __restrict__ outf, unsigned short* __restrict__ outb){
  __shared__ short lds[2 * LDSH];            // 48 KB double buffer
  const int tid = threadIdx.x;
  const int w = tid >> 6, l = tid & 63;
  const int wm = w >> 1, wn = w & 1;
  const int sub = l >> 4, llr = l & 15;
  const int mbase = blockIdx.x * 64;
  const size_t plane = (size_t)NN * 128;
  f32x4 acc[2][4] = {};

  int arow = mbase + l; if (arow > NN - 1) arow = NN - 1;   // staging row clamp

  // stage tile kt into buffer at short-offset `base`
#define STAGE(kt, base) do{ \
    const unsigned short* abase_ = ((kt) < 16) \
        ? Aa + (size_t)((kt) >> 1) * plane + (size_t)((kt) & 1) * 64 \
        : Ah + (size_t)((kt) - 16) * 64; \
    GLD16(abase_ + (size_t)arow * 128 + w * 8,       lds + (base) + (size_t)(w * 64) * 8); \
    GLD16(abase_ + (size_t)arow * 128 + (4 + w) * 8, lds + (base) + (size_t)(256 + w * 64) * 8); \
    const short* bsrc_ = Bp + (size_t)(kt) * 8192; \
    _Pragma("unroll") \
    for (int i_ = 0; i_ < 4; ++i_) \
      GLD16(bsrc_ + (size_t)(i_ * 256 + tid) * 8, \
            lds + (base) + (size_t)(4096 + (i_ * 256 + w * 64) * 8)); \
  }while(0)

  STAGE(0, 0);
  __syncthreads();
  int cur = 0;

#pragma unroll 1
  for (int kt = 0; kt < 18; ++kt){
    if (kt + 1 < 18) STAGE(kt + 1, (cur ^ 1) * LDSH);
    const short* lb = lds + cur * LDSH;
#pragma unroll
    for (int t = 0; t < 2; ++t){
      bf16x8 af0 = *(const bf16x8*)(lb + (size_t)(((t * 4 + sub) * 64) + wm * 32 + llr) * 8);
      bf16x8 af1 = *(const bf16x8*)(lb + (size_t)(((t * 4 + sub) * 64) + wm * 32 + 16 + llr) * 8);
#pragma unroll
      for (int nf = 0; nf < 4; ++nf){
        bf16x8 bq = *(const bf16x8*)(lb + (size_t)(4096 + (t * 8 + wn * 4 + nf) * 512 + l * 8));
        acc[0][nf] = __builtin_amdgcn_mfma_f32_16x16x32_bf16(af0, bq, acc[0][nf], 0, 0, 0);
        acc[1][nf] = __builtin_amdgcn_mfma_f32_16x16x32_bf16(af1, bq, acc[1][nf], 0, 0, 0);
      }
    }
    __syncthreads();                         // drains next-tile loads (overlapped)
    cur ^= 1;
  }
#undef STAGE

  const int lr = l >> 4, lc = l & 15;
#pragma unroll
  for (int mf = 0; mf < 2; ++mf){
#pragma unroll
    for (int nf = 0; nf < 4; ++nf){
      int col = wn * 64 + nf * 16 + lc;
      float bv = bias[col];
#pragma unroll
      for (int r = 0; r < 4; ++r){
        int row = mbase + wm * 32 + mf * 16 + lr * 4 + r;
        if (row < NN){
          float v = acc[mf][nf][r] + bv;
          v = bf2f(resb[(size_t)row * 128 + col]) + fmaxf(v, 0.f);
          if (OUTMODE == 1) outb[(size_t)row * 128 + col] = f2bf(v);
          else              outf[(size_t)row * 128 + col] = v;
        }
      }
    }
  }
}

extern "C" void kernel_launch(void* const* d_in, const int* in_sizes, int n_in,
                              void* d_out, int out_size, void* d_ws, size_t ws_size,
                              hipStream_t stream){
  const float* x  = (const float*)d_in[0];
  const int*   ei = (const int*)d_in[1];
  const int*   et = (const int*)d_in[2];
  const float* W1 = (const float*)d_in[3];
  const float* r1 = (const float*)d_in[4];
  const float* b1 = (const float*)d_in[5];
  const float* W2 = (const float*)d_in[6];
  const float* r2 = (const float*)d_in[7];
  const float* b2 = (const float*)d_in[8];
  const float* W3 = (const float*)d_in[9];
  const float* r3 = (const float*)d_in[10];
  const float* b3 = (const float*)d_in[11];
  const float* rw = (const float*)d_in[12];
  const float* rb = (const float*)d_in[13];
  const int* srcv = ei;
  const int* dstv = ei + EE;

  char* p = (char*)d_ws;
  auto take = [&](size_t b)->char*{ char* q = p; p += (b + 255) & ~(size_t)255; return q; };
  unsigned short* a    = (unsigned short*)take((size_t)NN * 1024 * 2);  // [R][NN][128]
  unsigned short* xb   = (unsigned short*)take((size_t)NN * 128 * 2);
  unsigned short* h1   = (unsigned short*)take((size_t)NN * 128 * 2);
  unsigned short* h2   = (unsigned short*)take((size_t)NN * 128 * 2);
  unsigned short* resb = (unsigned short*)take((size_t)NN * 128 * 2);
  short* Bp1 = (short*)take(36 * 4096 * 2);
  short* Bp2 = (short*)take(36 * 4096 * 2);
  short* Bp3 = (short*)take(36 * 4096 * 2);
  short* BpR = (short*)take(4 * 4096 * 2);
  u32* cnt   = (u32*)take((size_t)NSEG * 4);
  u32* offs  = (u32*)take((size_t)(NSEG + 1) * 4);
  int* elist = (int*)take((size_t)EE * 4);
  u32* bsum  = (u32*)take((size_t)NB_SCAN * 4);

  hipMemsetAsync(cnt, 0, (size_t)NSEG * 4, stream);

  // conversions + weight packing (once)
  cvt_k<<<(NN * 128 / 4 + 255) / 256, 256, 0, stream>>>(x, xb, NN * 128 / 4);
  pack_k<<<(36 * 512 + 255) / 256, 256, 0, stream>>>(W1, r1, Bp1, 36, 1024);
  pack_k<<<(36 * 512 + 255) / 256, 256, 0, stream>>>(W2, r2, Bp2, 36, 1024);
  pack_k<<<(36 * 512 + 255) / 256, 256, 0, stream>>>(W3, r3, Bp3, 36, 1024);
  pack_k<<<(4 * 512 + 255) / 256, 256, 0, stream>>>(nullptr, rw, BpR, 4, 0);

  // CSR over segments (etype*NN + dst), once for all layers
  count_k<<<(EE + 255) / 256, 256, 0, stream>>>(dstv, et, cnt);
  scan1_k<<<NB_SCAN, 256, 0, stream>>>(cnt, offs, bsum);
  scan2_k<<<1, 512, 0, stream>>>(bsum);
  scan3_k<<<NB_SCAN, 256, 0, stream>>>(offs, bsum);
  fill_k<<<(EE + 255) / 256, 256, 0, stream>>>(srcv, dstv, et, offs, cnt, elist);

  const int GB = (NN + 63) / 64;  // 782

  // res = bf16(x @ res_w + res_b)
  resg_k<<<GB, 256, 0, stream>>>(xb, BpR, rb, resb);

  // layer 1
  agg_k<<<NSEG / 32, 256, 0, stream>>>(offs, elist, xb, a);
  gemm_k<1><<<GB, 256, 0, stream>>>(a, xb, Bp1, b1, resb, nullptr, h1);
  // layer 2
  agg_k<<<NSEG / 32, 256, 0, stream>>>(offs, elist, h1, a);
  gemm_k<1><<<GB, 256, 0, stream>>>(a, h1, Bp2, b2, resb, nullptr, h2);
  // layer 3
  agg_k<<<NSEG / 32, 256, 0, stream>>>(offs, elist, h2, a);
  gemm_k<2><<<GB, 256, 0, stream>>>(a, h2, Bp3, b3, resb, (float*)d_out, nullptr);
}

// Round 11
// 353.322 us; speedup vs baseline: 1.0327x; 1.0327x over previous
//
#include <hip/hip_runtime.h>
#include <hip/hip_bf16.h>

#define NN 50000
#define EE 600000
#define RR 8
#define NSEG (NN*RR)                     // 400000
#define NB_SCAN ((NSEG + 1023)/1024)     // 391
#define LDSH 12288                       // shorts per buffer (A 4096 | B 8192)

typedef unsigned int u32;
typedef __attribute__((ext_vector_type(8))) short bf16x8;
typedef __attribute__((ext_vector_type(4))) float f32x4;
typedef __attribute__((ext_vector_type(4))) u32 u32x4;

// fp32 -> bf16 round-to-nearest-even (finite inputs only)
__device__ inline unsigned short f2bf(float f){
  u32 u = __float_as_uint(f);
  u32 r = (u + 0x7fffu + ((u >> 16) & 1u)) >> 16;
  return (unsigned short)r;
}
__device__ inline float bf2f(unsigned short b){ return __uint_as_float((u32)b << 16); }

#define GLD16(g, l)  __builtin_amdgcn_global_load_lds( \
    (const __attribute__((address_space(1))) void*)(g), \
    (__attribute__((address_space(3))) void*)(l), 16, 0, 0)

// ---------------- conversion: fp32 -> bf16, 4 elems/thread ----------------
__global__ void cvt_k(const float* __restrict__ in, unsigned short* __restrict__ out, int n4){
  int i = blockIdx.x * 256 + threadIdx.x;
  if (i >= n4) return;
  float4 v = ((const float4*)in)[i];
  ushort4 o;
  o.x = f2bf(v.x); o.y = f2bf(v.y); o.z = f2bf(v.z); o.w = f2bf(v.w);
  ((ushort4*)out)[i] = o;
}

// ---------------- pack B (W stack) into MFMA fragment order ----------------
// frag id = k32*8 + nf; within frag: lane*8 + i
// element: B[k32*32 + (lane>>4)*8 + i][nf*16 + (lane&15)]
__global__ void pack_k(const float* __restrict__ Wrel, const float* __restrict__ root,
                       short* __restrict__ Bp, int nk32, int krel){
  int tid = blockIdx.x * 256 + threadIdx.x;
  if (tid >= nk32 * 512) return;
  int lane = tid & 63;
  int nf   = (tid >> 6) & 7;
  int k32  = tid >> 9;
  int col  = nf * 16 + (lane & 15);
  short vals[8];
#pragma unroll
  for (int i = 0; i < 8; ++i){
    int kk = k32 * 32 + ((lane >> 4) << 3) + i;
    float f = (kk < krel) ? Wrel[(size_t)kk * 128 + col]
                          : root[(size_t)(kk - krel) * 128 + col];
    vals[i] = (short)f2bf(f);
  }
  *(bf16x8*)(Bp + (size_t)tid * 8) = *(const bf16x8*)vals;
}

// ---------------- CSR build (relation-major: seg = r*NN + dst) -------------
__global__ void count_k(const int* __restrict__ dst, const int* __restrict__ et,
                        u32* __restrict__ cnt){
  int e = blockIdx.x * 256 + threadIdx.x;
  if (e >= EE) return;
  atomicAdd(&cnt[(size_t)et[e] * NN + dst[e]], 1u);
}

__global__ void scan1_k(const u32* __restrict__ cnt, u32* __restrict__ offs, u32* __restrict__ bsum){
  __shared__ u32 s[512];
  int t = threadIdx.x;                       // 256 threads
  int base = blockIdx.x * 1024 + t * 4;
  u32 loc[4]; u32 sum = 0;
#pragma unroll
  for (int i = 0; i < 4; ++i){ loc[i] = (base + i < NSEG) ? cnt[base + i] : 0u; sum += loc[i]; }
  int pb = 0;
  s[t] = sum; __syncthreads();
  for (int off = 1; off < 256; off <<= 1){
    u32 v = s[pb * 256 + t];
    if (t >= off) v += s[pb * 256 + t - off];
    s[(pb ^ 1) * 256 + t] = v; pb ^= 1; __syncthreads();
  }
  u32 incl = s[pb * 256 + t];
  u32 excl = incl - sum;
  if (t == 255) bsum[blockIdx.x] = incl;
  u32 run = excl;
#pragma unroll
  for (int i = 0; i < 4; ++i){ if (base + i < NSEG) offs[base + i] = run; run += loc[i]; }
}

__global__ void scan2_k(u32* __restrict__ bsum){
  __shared__ u32 s[1024];
  int t = threadIdx.x;                       // 512 threads
  u32 v = (t < NB_SCAN) ? bsum[t] : 0u;
  int pb = 0;
  s[t] = v; __syncthreads();
  for (int off = 1; off < 512; off <<= 1){
    u32 x = s[pb * 512 + t];
    if (t >= off) x += s[pb * 512 + t - off];
    s[(pb ^ 1) * 512 + t] = x; pb ^= 1; __syncthreads();
  }
  u32 incl = s[pb * 512 + t];
  if (t < NB_SCAN) bsum[t] = incl - v;       // exclusive
}

__global__ void scan3_k(u32* __restrict__ offs, const u32* __restrict__ bsum){
  int t = threadIdx.x;
  int base = blockIdx.x * 1024 + t * 4;
  u32 add = bsum[blockIdx.x];
#pragma unroll
  for (int i = 0; i < 4; ++i){ if (base + i < NSEG) offs[base + i] += add; }
  if (blockIdx.x == 0 && t == 0) offs[NSEG] = EE;
}

// fill: reuse cnt as cursor (atomicSub)
__global__ void fill_k(const int* __restrict__ src, const int* __restrict__ dst,
                       const int* __restrict__ et, const u32* __restrict__ offs,
                       u32* __restrict__ cnt, int* __restrict__ elist){
  int e = blockIdx.x * 256 + threadIdx.x;
  if (e >= EE) return;
  int s = et[e] * NN + dst[e];
  u32 p = atomicSub(&cnt[s], 1u);
  elist[offs[s] + p - 1] = src[e];
}

// ------- per-(relation,dst) mean aggregation -> a[R][NN][128] bf16 ----------
// 8-lane group per segment, 32 segments/block; lane owns 32 B of the row.
__launch_bounds__(256, 8)
__global__ void agg_k(const u32* __restrict__ offs, const int* __restrict__ elist,
                      const unsigned short* __restrict__ h, unsigned short* __restrict__ a){
  int t = threadIdx.x;
  int g = t >> 3, ll8 = t & 7;
  int seg = blockIdx.x * 32 + g;
  u32 beg = offs[seg], end = offs[seg + 1];
  float s[16];
#pragma unroll
  for (int i = 0; i < 16; ++i) s[i] = 0.f;
  const unsigned short* hb = h + (size_t)ll8 * 16;
  u32 e = beg;
  for (; e + 2 <= end; e += 2){
    int s0 = elist[e], s1 = elist[e + 1];
    const unsigned short* r0 = hb + (size_t)s0 * 128;
    const unsigned short* r1 = hb + (size_t)s1 * 128;
    u32x4 p00 = *(const u32x4*)r0, p01 = *(const u32x4*)(r0 + 8);
    u32x4 p10 = *(const u32x4*)r1, p11 = *(const u32x4*)(r1 + 8);
#pragma unroll
    for (int i = 0; i < 4; ++i){
      s[2*i]     += __uint_as_float(p00[i] << 16)         + __uint_as_float(p10[i] << 16);
      s[2*i+1]   += __uint_as_float(p00[i] & 0xffff0000u) + __uint_as_float(p10[i] & 0xffff0000u);
      s[8+2*i]   += __uint_as_float(p01[i] << 16)         + __uint_as_float(p11[i] << 16);
      s[8+2*i+1] += __uint_as_float(p01[i] & 0xffff0000u) + __uint_as_float(p11[i] & 0xffff0000u);
    }
  }
  if (e < end){
    int s0 = elist[e];
    const unsigned short* r0 = hb + (size_t)s0 * 128;
    u32x4 p00 = *(const u32x4*)r0, p01 = *(const u32x4*)(r0 + 8);
#pragma unroll
    for (int i = 0; i < 4; ++i){
      s[2*i]     += __uint_as_float(p00[i] << 16);
      s[2*i+1]   += __uint_as_float(p00[i] & 0xffff0000u);
      s[8+2*i]   += __uint_as_float(p01[i] << 16);
      s[8+2*i+1] += __uint_as_float(p01[i] & 0xffff0000u);
    }
  }
  u32 deg = end - beg;
  if (deg){
    float inv = 1.f / (float)deg;
#pragma unroll
    for (int i = 0; i < 16; ++i) s[i] *= inv;
  }
  u32x4 o0, o1;
#pragma unroll
  for (int i = 0; i < 4; ++i){
    o0[i] = (u32)f2bf(s[2*i])   | ((u32)f2bf(s[2*i+1])   << 16);
    o1[i] = (u32)f2bf(s[8+2*i]) | ((u32)f2bf(s[8+2*i+1]) << 16);
  }
  unsigned short* ap = a + (size_t)seg * 128 + ll8 * 16;
  *(u32x4*)ap = o0;
  *(u32x4*)(ap + 8) = o1;
}

// ---------------- res projection: resb = bf16(x @ res_w + res_b) ----------
__launch_bounds__(256, 4)
__global__ void resg_k(const unsigned short* __restrict__ xb, const short* __restrict__ Bp,
                       const float* __restrict__ rb, unsigned short* __restrict__ resb){
  const int tid = threadIdx.x;
  const int w = tid >> 6, l = tid & 63;
  const int sub = l >> 4, llr = l & 15;
  const int rowbase = blockIdx.x * 64 + w * 16;
  int vr = rowbase + llr; if (vr > NN - 1) vr = NN - 1;
  f32x4 acc[8] = {};
#pragma unroll
  for (int t = 0; t < 4; ++t){
    bf16x8 af = *(const bf16x8*)(xb + (size_t)vr * 128 + (t * 4 + sub) * 8);
    const short* bb = Bp + (size_t)(t * 8) * 512 + l * 8;
#pragma unroll
    for (int nf = 0; nf < 8; ++nf){
      bf16x8 bq = *(const bf16x8*)(bb + nf * 512);
      acc[nf] = __builtin_amdgcn_mfma_f32_16x16x32_bf16(af, bq, acc[nf], 0, 0, 0);
    }
  }
  const int lr = l >> 4, lc = l & 15;
#pragma unroll
  for (int nf = 0; nf < 8; ++nf){
    int col = nf * 16 + lc;
    float bv = rb[col];
#pragma unroll
    for (int r = 0; r < 4; ++r){
      int row = rowbase + lr * 4 + r;
      if (row < NN) resb[(size_t)row * 128 + col] = f2bf(acc[nf][r] + bv);
    }
  }
}

// -------- MFMA GEMM: 3-buffer depth-2 pipeline, counted vmcnt, raw barriers -
// BM=64, BN=128, BK=64. 4 waves: wave (wm,wn) owns 32 rows x 64 cols.
// Fully unrolled: buffer indices are compile-time (compiler can disambiguate).
// Per kt: issue STAGE(kt+2); vmcnt(12) keeps tiles kt+1,kt+2 in flight while
// ensuring tile kt landed; raw barrier; compute; raw barrier (WAR fence).
template<int OUTMODE>
__launch_bounds__(256, 2)
__global__ void gemm_k(const unsigned short* __restrict__ Aa,   // [R][NN][128]
                       const unsigned short* __restrict__ Ah,   // [NN][128]
                       const short* __restrict__ Bp,            // 18*8192 shorts packed
                       const float* __restrict__ bias,
                       const unsigned short* __restrict__ resb,
                       float* __restrict__ outf, unsigned short* __restrict__ outb){
  __shared__ short lds[3 * LDSH];            // 72 KB triple buffer
  const int tid = threadIdx.x;
  const int w = tid >> 6, l = tid & 63;
  const int wm = w >> 1, wn = w & 1;
  const int sub = l >> 4, llr = l & 15;
  const int mbase = blockIdx.x * 64;
  const size_t plane = (size_t)NN * 128;
  f32x4 acc[2][4] = {};

  int arow = mbase + l; if (arow > NN - 1) arow = NN - 1;   // staging row clamp

#define STAGE(kt, base) do{ \
    const unsigned short* abase_ = ((kt) < 16) \
        ? Aa + (size_t)((kt) >> 1) * plane + (size_t)((kt) & 1) * 64 \
        : Ah + (size_t)((kt) - 16) * 64; \
    GLD16(abase_ + (size_t)arow * 128 + w * 8,       lds + (base) + (size_t)(w * 64) * 8); \
    GLD16(abase_ + (size_t)arow * 128 + (4 + w) * 8, lds + (base) + (size_t)(256 + w * 64) * 8); \
    const short* bsrc_ = Bp + (size_t)(kt) * 8192; \
    _Pragma("unroll") \
    for (int i_ = 0; i_ < 4; ++i_) \
      GLD16(bsrc_ + (size_t)(i_ * 256 + tid) * 8, \
            lds + (base) + (size_t)(4096 + (i_ * 256 + w * 64) * 8)); \
  }while(0)

  STAGE(0, 0);
  STAGE(1, LDSH);

#pragma unroll
  for (int kt = 0; kt < 18; ++kt){
    if (kt + 2 < 18) STAGE(kt + 2, ((kt + 2) % 3) * LDSH);
    // counted wait: tile kt landed; tiles kt+1,kt+2 (<=12 loads) stay in flight
    if (kt < 16)      asm volatile("s_waitcnt vmcnt(12)" ::: "memory");
    else if (kt == 16) asm volatile("s_waitcnt vmcnt(6)"  ::: "memory");
    else               asm volatile("s_waitcnt vmcnt(0)"  ::: "memory");
    __builtin_amdgcn_sched_barrier(0);
    __builtin_amdgcn_s_barrier();            // all waves' tile-kt stores visible
    const short* lb = lds + (kt % 3) * LDSH;
#pragma unroll
    for (int t = 0; t < 2; ++t){
      bf16x8 af0 = *(const bf16x8*)(lb + (size_t)(((t * 4 + sub) * 64) + wm * 32 + llr) * 8);
      bf16x8 af1 = *(const bf16x8*)(lb + (size_t)(((t * 4 + sub) * 64) + wm * 32 + 16 + llr) * 8);
#pragma unroll
      for (int nf = 0; nf < 4; ++nf){
        bf16x8 bq = *(const bf16x8*)(lb + (size_t)(4096 + (t * 8 + wn * 4 + nf) * 512 + l * 8));
        acc[0][nf] = __builtin_amdgcn_mfma_f32_16x16x32_bf16(af0, bq, acc[0][nf], 0, 0, 0);
        acc[1][nf] = __builtin_amdgcn_mfma_f32_16x16x32_bf16(af1, bq, acc[1][nf], 0, 0, 0);
      }
    }
    asm volatile("s_waitcnt lgkmcnt(0)" ::: "memory");   // reads of lb done
    __builtin_amdgcn_sched_barrier(0);
    __builtin_amdgcn_s_barrier();            // WAR fence before buffer reuse
  }
#undef STAGE

  const int lr = l >> 4, lc = l & 15;
#pragma unroll
  for (int mf = 0; mf < 2; ++mf){
#pragma unroll
    for (int nf = 0; nf < 4; ++nf){
      int col = wn * 64 + nf * 16 + lc;
      float bv = bias[col];
#pragma unroll
      for (int r = 0; r < 4; ++r){
        int row = mbase + wm * 32 + mf * 16 + lr * 4 + r;
        if (row < NN){
          float v = acc[mf][nf][r] + bv;
          v = bf2f(resb[(size_t)row * 128 + col]) + fmaxf(v, 0.f);
          if (OUTMODE == 1) outb[(size_t)row * 128 + col] = f2bf(v);
          else              outf[(size_t)row * 128 + col] = v;
        }
      }
    }
  }
}

extern "C" void kernel_launch(void* const* d_in, const int* in_sizes, int n_in,
                              void* d_out, int out_size, void* d_ws, size_t ws_size,
                              hipStream_t stream){
  const float* x  = (const float*)d_in[0];
  const int*   ei = (const int*)d_in[1];
  const int*   et = (const int*)d_in[2];
  const float* W1 = (const float*)d_in[3];
  const float* r1 = (const float*)d_in[4];
  const float* b1 = (const float*)d_in[5];
  const float* W2 = (const float*)d_in[6];
  const float* r2 = (const float*)d_in[7];
  const float* b2 = (const float*)d_in[8];
  const float* W3 = (const float*)d_in[9];
  const float* r3 = (const float*)d_in[10];
  const float* b3 = (const float*)d_in[11];
  const float* rw = (const float*)d_in[12];
  const float* rb = (const float*)d_in[13];
  const int* srcv = ei;
  const int* dstv = ei + EE;

  char* p = (char*)d_ws;
  auto take = [&](size_t b)->char*{ char* q = p; p += (b + 255) & ~(size_t)255; return q; };
  unsigned short* a    = (unsigned short*)take((size_t)NN * 1024 * 2);  // [R][NN][128]
  unsigned short* xb   = (unsigned short*)take((size_t)NN * 128 * 2);
  unsigned short* h1   = (unsigned short*)take((size_t)NN * 128 * 2);
  unsigned short* h2   = (unsigned short*)take((size_t)NN * 128 * 2);
  unsigned short* resb = (unsigned short*)take((size_t)NN * 128 * 2);
  short* Bp1 = (short*)take(36 * 4096 * 2);
  short* Bp2 = (short*)take(36 * 4096 * 2);
  short* Bp3 = (short*)take(36 * 4096 * 2);
  short* BpR = (short*)take(4 * 4096 * 2);
  u32* cnt   = (u32*)take((size_t)NSEG * 4);
  u32* offs  = (u32*)take((size_t)(NSEG + 1) * 4);
  int* elist = (int*)take((size_t)EE * 4);
  u32* bsum  = (u32*)take((size_t)NB_SCAN * 4);

  hipMemsetAsync(cnt, 0, (size_t)NSEG * 4, stream);

  // conversions + weight packing (once)
  cvt_k<<<(NN * 128 / 4 + 255) / 256, 256, 0, stream>>>(x, xb, NN * 128 / 4);
  pack_k<<<(36 * 512 + 255) / 256, 256, 0, stream>>>(W1, r1, Bp1, 36, 1024);
  pack_k<<<(36 * 512 + 255) / 256, 256, 0, stream>>>(W2, r2, Bp2, 36, 1024);
  pack_k<<<(36 * 512 + 255) / 256, 256, 0, stream>>>(W3, r3, Bp3, 36, 1024);
  pack_k<<<(4 * 512 + 255) / 256, 256, 0, stream>>>(nullptr, rw, BpR, 4, 0);

  // CSR over segments (etype*NN + dst), once for all layers
  count_k<<<(EE + 255) / 256, 256, 0, stream>>>(dstv, et, cnt);
  scan1_k<<<NB_SCAN, 256, 0, stream>>>(cnt, offs, bsum);
  scan2_k<<<1, 512, 0, stream>>>(bsum);
  scan3_k<<<NB_SCAN, 256, 0, stream>>>(offs, bsum);
  fill_k<<<(EE + 255) / 256, 256, 0, stream>>>(srcv, dstv, et, offs, cnt, elist);

  const int GB = (NN + 63) / 64;  // 782

  // res = bf16(x @ res_w + res_b)
  resg_k<<<GB, 256, 0, stream>>>(xb, BpR, rb, resb);

  // layer 1
  agg_k<<<NSEG / 32, 256, 0, stream>>>(offs, elist, xb, a);
  gemm_k<1><<<GB, 256, 0, stream>>>(a, xb, Bp1, b1, resb, nullptr, h1);
  // layer 2
  agg_k<<<NSEG / 32, 256, 0, stream>>>(offs, elist, h1, a);
  gemm_k<1><<<GB, 256, 0, stream>>>(a, h1, Bp2, b2, resb, nullptr, h2);
  // layer 3
  agg_k<<<NSEG / 32, 256, 0, stream>>>(offs, elist, h2, a);
  gemm_k<2><<<GB, 256, 0, stream>>>(a, h2, Bp3, b3, resb, (float*)d_out, nullptr);
}